// Round 1
// baseline (34.031 us; speedup 1.0000x reference)
//
#include <hip/hip_runtime.h>
#include <cmath>

namespace {

constexpr int KQ   = 8;     // quantile subchannels
constexpr int NVH  = 256;   // hi-res velocity bins
constexpr int NVL  = 64;    // lo-res velocity bins
constexpr int NPH  = 512;   // hi-res image size
constexpr int NPL  = 128;   // lo-res image size
constexpr int HPAD = NVH + 1; // padded histogram stride (bank decorrelation)

struct Units { float u[KQ]; };

__global__ __launch_bounds__(256)
void lens_cube_kernel(const float* __restrict__ p_inc,
                      const float* __restrict__ p_rot,
                      const float* __restrict__ p_sig,
                      const float* __restrict__ p_vsh,
                      const float* __restrict__ p_x0,
                      const float* __restrict__ p_y0,
                      const float* __restrict__ p_dist,
                      const float* __restrict__ p_thE,
                      const float* __restrict__ p_I0,
                      const float* __restrict__ p_Rd,
                      const float* __restrict__ p_vmax,
                      const float* __restrict__ p_Rt,
                      float* __restrict__ out,
                      Units units)
{
    // 16 lo pixels per block, each with a 256-bin hi-res velocity histogram.
    __shared__ float hist[16][HPAD];   // ~16.4 KB

    const int tid = threadIdx.x;

    // ---- zero histograms ----
    float* hflat = &hist[0][0];
    #pragma unroll
    for (int i = tid; i < 16 * HPAD; i += 256) hflat[i] = 0.0f;

    // ---- scalar params (L1/L2-cached broadcast loads) ----
    const float inc  = *p_inc;
    const float rot  = *p_rot;
    const float sig  = fabsf(*p_sig) + 1e-12f;
    const float vsh  = *p_vsh;
    const float x0   = *p_x0;
    const float y0   = *p_y0;
    const float dist = *p_dist;
    const float thE  = *p_thE;
    const float I0   = *p_I0;
    const float Rd   = *p_Rd;
    const float vmax = *p_vmax;
    const float Rt   = *p_Rt;

    float sin_i, cos_i;
    sincosf(inc, &sin_i, &cos_i);
    const float pa = rot + (float)(M_PI / 2.0);
    float sp, cp;
    sincosf(pa, &sp, &cp);
    const float aspp = 206265.0f / dist;   // arcsec per pc

    // grid constants (double-evaluated, cast to f32 like the reference)
    const float PIX   = (float)(0.05 / 4.0);
    const float FOVH  = (float)(0.5 * (NPH - 1) * (0.05 / 4.0));
    const float VEL0  = (float)(-320.0 - 0.5 * (10.0 - 10.0 / 4.0)); // -323.75
    const float INVDV = (float)(1.0 / (10.0 / 4.0));                 // 0.4

    // ---- per-thread hi-res pixel ----
    const int tx  = tid & 63;          // 0..63 -> hi x within tile
    const int ty  = tid >> 6;          // 0..3  -> hi y within lo row
    const int lp  = tx >> 2;           // 0..15 -> lo pixel within tile
    const int xhi = blockIdx.x * 64 + tx;
    const int yhi = blockIdx.y * 4  + ty;

    const float thx = -FOVH + PIX * (float)xhi;
    const float thy = -FOVH + PIX * (float)yhi;

    // SIS raytrace
    const float r  = sqrtf(thx * thx + thy * thy) + 1e-12f;
    const float bx = thx - thE * thx / r;
    const float by = thy - thE * thy / r;

    // invert sky projection
    const float X  = (bx - x0) / aspp;
    const float Y  = (by - y0) / aspp;
    const float xg =  cp * X + sp * Y;
    const float yg = (-sp * X + cp * Y) / (cos_i + 1e-12f);
    const float R  = sqrtf(xg * xg + yg * yg);

    // analytic intensity / LOS velocity
    const float Iw   = I0 * expf(-R / Rd);
    const float vc   = vmax * (float)(2.0 / M_PI) * atanf(R / Rt);
    const float vlos = vc * sin_i * (xg / (R + 1e-12f)) + vsh;

    __syncthreads();   // histograms zeroed

    // ---- K quantile channels -> linear binning into LDS histogram ----
    float* h = hist[lp];
    #pragma unroll
    for (int k = 0; k < KQ; ++k) {
        const float vs  = vlos + sig * units.u[k];
        const float ivf = (vs - VEL0) * INVDV;
        int iv0 = (int)floorf(ivf);
        iv0 = iv0 < 0 ? 0 : (iv0 > NVH - 1 ? NVH - 1 : iv0);
        const int iv1 = (iv0 + 1 > NVH - 1) ? NVH - 1 : iv0 + 1;
        float fv = ivf - (float)iv0;
        fv = fv < 0.0f ? 0.0f : (fv > 1.0f ? 1.0f : fv);
        atomicAdd(&h[iv0], (1.0f - fv) * Iw);
        atomicAdd(&h[iv1], fv * Iw);
    }

    __syncthreads();

    // ---- fold 256 hi bins -> 64 lo bins, scale by 1/(K * 4*4*4), store ----
    const int flp  = tid & 15;         // lo pixel
    const int vb   = tid >> 4;         // 0..15 base v
    const int xout = blockIdx.x * 16 + flp;
    const int base = (int)blockIdx.y * NPL + xout;
    const float* hh = hist[flp];
    #pragma unroll
    for (int p = 0; p < 4; ++p) {
        const int v = vb + 16 * p;
        const float s = hh[4 * v] + hh[4 * v + 1] + hh[4 * v + 2] + hh[4 * v + 3];
        out[v * (NPL * NPL) + base] = s * (1.0f / 512.0f);
    }
}

// host-side double-precision erfinv via Winitzki guess + Newton on std::erf
double erfinv_newton(double y) {
    if (y == 0.0) return 0.0;
    const double a  = 0.147;
    const double ln = std::log(1.0 - y * y);
    const double t  = 2.0 / (M_PI * a) + 0.5 * ln;
    double x = std::sqrt(std::sqrt(t * t - ln / a) - t);
    if (y < 0.0) x = -x;
    for (int i = 0; i < 4; ++i) {
        const double err = std::erf(x) - y;
        x -= err / (2.0 / std::sqrt(M_PI) * std::exp(-x * x));
    }
    return x;
}

} // namespace

extern "C" void kernel_launch(void* const* d_in, const int* in_sizes, int n_in,
                              void* d_out, int out_size, void* d_ws, size_t ws_size,
                              hipStream_t stream) {
    Units u;
    for (int k = 0; k < KQ; ++k) {
        const double p = (k + 0.5) / (double)KQ;
        u.u[k] = (float)(std::sqrt(2.0) * erfinv_newton(2.0 * p - 1.0));
    }

    const float* p_inc  = (const float*)d_in[0];
    const float* p_rot  = (const float*)d_in[1];
    const float* p_sig  = (const float*)d_in[2];
    const float* p_vsh  = (const float*)d_in[3];
    const float* p_x0   = (const float*)d_in[4];
    const float* p_y0   = (const float*)d_in[5];
    const float* p_dist = (const float*)d_in[6];
    const float* p_thE  = (const float*)d_in[7];
    const float* p_I0   = (const float*)d_in[8];
    const float* p_Rd   = (const float*)d_in[9];
    const float* p_vmax = (const float*)d_in[10];
    const float* p_Rt   = (const float*)d_in[11];

    dim3 grid(NPH / 64, NPH / 4);   // (8, 128) = 1024 blocks
    dim3 block(256);
    lens_cube_kernel<<<grid, block, 0, stream>>>(
        p_inc, p_rot, p_sig, p_vsh, p_x0, p_y0, p_dist, p_thE,
        p_I0, p_Rd, p_vmax, p_Rt, (float*)d_out, u);
}

// Round 2
// 25.677 us; speedup vs baseline: 1.3254x; 1.3254x over previous
//
#include <hip/hip_runtime.h>
#include <cmath>

namespace {

constexpr int KQ   = 8;     // quantile subchannels
constexpr int NVH  = 256;   // hi-res velocity bins
constexpr int NVL  = 64;    // lo-res velocity bins
constexpr int NPH  = 512;   // hi-res image size
constexpr int NPL  = 128;   // lo-res image size
constexpr int HPAD = NVL + 1; // 65: bank-decorrelating pad

struct Units { float u[KQ]; };

__device__ __forceinline__ void lds_fadd(float* p, float v) {
    // Relaxed workgroup-scope fp add on LDS -> native ds_add_f32 (no CAS loop).
    __hip_atomic_fetch_add(p, v, __ATOMIC_RELAXED, __HIP_MEMORY_SCOPE_WORKGROUP);
}

__global__ __launch_bounds__(256)
void lens_cube_kernel(const float* __restrict__ p_inc,
                      const float* __restrict__ p_rot,
                      const float* __restrict__ p_sig,
                      const float* __restrict__ p_vsh,
                      const float* __restrict__ p_x0,
                      const float* __restrict__ p_y0,
                      const float* __restrict__ p_dist,
                      const float* __restrict__ p_thE,
                      const float* __restrict__ p_I0,
                      const float* __restrict__ p_Rd,
                      const float* __restrict__ p_vmax,
                      const float* __restrict__ p_Rt,
                      float* __restrict__ out,
                      Units units)
{
    // 16 lo pixels per block, each with a 64-bin LO-res velocity histogram.
    // (Velocity downsample = sum of 4 consecutive hi bins, so lo = iv>>2 exactly.)
    __shared__ float hist[16][HPAD];   // 4.2 KB

    const int tid = threadIdx.x;

    // ---- zero histograms (1040 words) ----
    float* hflat = &hist[0][0];
    for (int i = tid; i < 16 * HPAD; i += 256) hflat[i] = 0.0f;

    // ---- scalar params (uniform broadcast loads) ----
    const float inc  = *p_inc;
    const float rot  = *p_rot;
    const float sig  = fabsf(*p_sig) + 1e-12f;
    const float vsh  = *p_vsh;
    const float x0   = *p_x0;
    const float y0   = *p_y0;
    const float dist = *p_dist;
    const float thE  = *p_thE;
    const float I0   = *p_I0;
    const float Rd   = *p_Rd;
    const float vmax = *p_vmax;
    const float Rt   = *p_Rt;

    float sin_i, cos_i;
    sincosf(inc, &sin_i, &cos_i);
    const float pa = rot + (float)(M_PI / 2.0);
    float sp, cp;
    sincosf(pa, &sp, &cp);
    // uniform reciprocals (hoisted, computed once)
    const float inv_aspp = dist * (float)(1.0 / 206265.0);  // pc per arcsec
    const float inv_cosi = 1.0f / (cos_i + 1e-12f);
    const float inv_Rd   = 1.0f / Rd;
    const float inv_Rt   = 1.0f / Rt;
    const float vfac     = vmax * (float)(2.0 / M_PI);

    // grid constants
    const float PIX   = (float)(0.05 / 4.0);
    const float FOVH  = (float)(0.5 * (NPH - 1) * (0.05 / 4.0));     // 3.19375
    const float VEL0  = (float)(-320.0 - 0.5 * (10.0 - 10.0 / 4.0)); // -323.75
    const float INVDV = (float)(4.0 / 10.0);                          // 0.4

    // ---- per-thread hi-res pixel ----
    const int tx  = tid & 63;          // hi x within tile
    const int ty  = tid >> 6;          // hi y within lo row
    const int lp  = tx >> 2;           // lo pixel within tile
    const int xhi = blockIdx.x * 64 + tx;
    const int yhi = blockIdx.y * 4  + ty;

    const float thx = -FOVH + PIX * (float)xhi;
    const float thy = -FOVH + PIX * (float)yhi;

    // SIS raytrace: beta = theta * (1 - thE/r)
    const float r    = sqrtf(thx * thx + thy * thy) + 1e-12f;
    const float defl = __fdividef(thE, r);
    const float bx   = thx - thx * defl;
    const float by   = thy - thy * defl;

    // invert sky projection
    const float X  = (bx - x0) * inv_aspp;
    const float Y  = (by - y0) * inv_aspp;
    const float xg =  cp * X + sp * Y;
    const float yg = (-sp * X + cp * Y) * inv_cosi;
    const float R  = sqrtf(xg * xg + yg * yg);

    // analytic intensity / LOS velocity
    const float Iw    = I0 * expf(-R * inv_Rd);
    const float vc    = vfac * atanf(R * inv_Rt);
    const float xfrac = __fdividef(xg, R + 1e-12f);
    const float vlos  = vc * sin_i * xfrac + vsh;

    __syncthreads();   // histograms zeroed

    // ---- K quantile channels -> linear binning, folded to lo bins ----
    float* h = hist[lp];
    #pragma unroll
    for (int k = 0; k < KQ; ++k) {
        const float vs  = vlos + sig * units.u[k];
        const float ivf = (vs - VEL0) * INVDV;
        int iv0 = (int)floorf(ivf);
        iv0 = iv0 < 0 ? 0 : (iv0 > NVH - 1 ? NVH - 1 : iv0);
        const int iv1 = (iv0 + 1 > NVH - 1) ? NVH - 1 : iv0 + 1;
        const int l0 = iv0 >> 2;
        const int l1 = iv1 >> 2;
        if (l0 == l1) {
            // both interp endpoints in same lo bin: weights sum to Iw exactly
            lds_fadd(&h[l0], Iw);
        } else {
            float fv = ivf - (float)iv0;
            fv = fv < 0.0f ? 0.0f : (fv > 1.0f ? 1.0f : fv);
            lds_fadd(&h[l0], Iw * (1.0f - fv));
            lds_fadd(&h[l1], Iw * fv);
        }
    }

    __syncthreads();

    // ---- store: 1024 outputs/block, scale by 1/(K * 4*4*4) = 1/512 ----
    const int xbase = blockIdx.x * 16;
    const int ybase = (int)blockIdx.y * NPL;
    #pragma unroll
    for (int p = 0; p < 4; ++p) {
        const int o   = tid + 256 * p;
        const int v   = o >> 4;
        const int flp = o & 15;
        out[v * (NPL * NPL) + ybase + xbase + flp] = hist[flp][v] * (1.0f / 512.0f);
    }
}

// host-side double-precision erfinv via Winitzki guess + Newton on std::erf
double erfinv_newton(double y) {
    if (y == 0.0) return 0.0;
    const double a  = 0.147;
    const double ln = std::log(1.0 - y * y);
    const double t  = 2.0 / (M_PI * a) + 0.5 * ln;
    double x = std::sqrt(std::sqrt(t * t - ln / a) - t);
    if (y < 0.0) x = -x;
    for (int i = 0; i < 4; ++i) {
        const double err = std::erf(x) - y;
        x -= err / (2.0 / std::sqrt(M_PI) * std::exp(-x * x));
    }
    return x;
}

} // namespace

extern "C" void kernel_launch(void* const* d_in, const int* in_sizes, int n_in,
                              void* d_out, int out_size, void* d_ws, size_t ws_size,
                              hipStream_t stream) {
    Units u;
    for (int k = 0; k < KQ; ++k) {
        const double p = (k + 0.5) / (double)KQ;
        u.u[k] = (float)(std::sqrt(2.0) * erfinv_newton(2.0 * p - 1.0));
    }

    const float* p_inc  = (const float*)d_in[0];
    const float* p_rot  = (const float*)d_in[1];
    const float* p_sig  = (const float*)d_in[2];
    const float* p_vsh  = (const float*)d_in[3];
    const float* p_x0   = (const float*)d_in[4];
    const float* p_y0   = (const float*)d_in[5];
    const float* p_dist = (const float*)d_in[6];
    const float* p_thE  = (const float*)d_in[7];
    const float* p_I0   = (const float*)d_in[8];
    const float* p_Rd   = (const float*)d_in[9];
    const float* p_vmax = (const float*)d_in[10];
    const float* p_Rt   = (const float*)d_in[11];

    dim3 grid(NPH / 64, NPH / 4);   // (8, 128) = 1024 blocks
    dim3 block(256);
    lens_cube_kernel<<<grid, block, 0, stream>>>(
        p_inc, p_rot, p_sig, p_vsh, p_x0, p_y0, p_dist, p_thE,
        p_I0, p_Rd, p_vmax, p_Rt, (float*)d_out, u);
}

// Round 3
// 25.364 us; speedup vs baseline: 1.3417x; 1.0123x over previous
//
#include <hip/hip_runtime.h>
#include <cmath>

namespace {

constexpr int KQ   = 8;     // quantile subchannels
constexpr int NVH  = 256;   // hi-res velocity bins
constexpr int NVL  = 64;    // lo-res velocity bins
constexpr int NPH  = 512;   // hi-res image size
constexpr int NPL  = 128;   // lo-res image size
constexpr int HPAD = NVL + 1; // 65: bank-decorrelating pad

struct Units { float u[KQ]; };

__device__ __forceinline__ void lds_fadd(float* p, float v) {
    // Relaxed workgroup-scope fp add on LDS -> native ds_add_f32 (no CAS loop).
    __hip_atomic_fetch_add(p, v, __ATOMIC_RELAXED, __HIP_MEMORY_SCOPE_WORKGROUP);
}

// fast atan for x >= 0: odd minimax poly on [0,1], rcp range-reduction above 1.
// max error ~1e-6 rad.
__device__ __forceinline__ float fast_atan_pos(float x) {
    const bool big = x > 1.0f;
    const float z  = big ? __builtin_amdgcn_rcpf(x) : x;   // z in [0,1]
    const float s  = z * z;
    float p = -0.0117212f;
    p = fmaf(p, s,  0.05265332f);
    p = fmaf(p, s, -0.11643287f);
    p = fmaf(p, s,  0.19354346f);
    p = fmaf(p, s, -0.33262347f);
    p = fmaf(p, s,  0.99997726f);
    const float a = p * z;
    return big ? (float)(M_PI / 2.0) - a : a;
}

__global__ __launch_bounds__(256)
void lens_cube_kernel(const float* __restrict__ p_inc,
                      const float* __restrict__ p_rot,
                      const float* __restrict__ p_sig,
                      const float* __restrict__ p_vsh,
                      const float* __restrict__ p_x0,
                      const float* __restrict__ p_y0,
                      const float* __restrict__ p_dist,
                      const float* __restrict__ p_thE,
                      const float* __restrict__ p_I0,
                      const float* __restrict__ p_Rd,
                      const float* __restrict__ p_vmax,
                      const float* __restrict__ p_Rt,
                      float* __restrict__ out,
                      Units units)
{
    // 16 lo pixels per block, each with a 64-bin LO-res velocity histogram.
    __shared__ float hist[16][HPAD];   // 4.2 KB

    const int tid = threadIdx.x;

    // ---- zero histograms (1040 words) ----
    float* hflat = &hist[0][0];
    for (int i = tid; i < 16 * HPAD; i += 256) hflat[i] = 0.0f;

    // ---- scalar params (uniform broadcast loads) ----
    const float inc  = *p_inc;
    const float rot  = *p_rot;
    const float sig  = fabsf(*p_sig) + 1e-12f;
    const float vsh  = *p_vsh;
    const float x0   = *p_x0;
    const float y0   = *p_y0;
    const float dist = *p_dist;
    const float thE  = *p_thE;
    const float I0   = *p_I0;
    const float Rd   = *p_Rd;
    const float vmax = *p_vmax;
    const float Rt   = *p_Rt;

    const float sin_i = __sinf(inc);
    const float cos_i = __cosf(inc);
    const float pa    = rot + (float)(M_PI / 2.0);
    const float sp    = __sinf(pa);
    const float cp    = __cosf(pa);

    const float inv_aspp = dist * (float)(1.0 / 206265.0);  // pc per arcsec
    const float inv_cosi = __builtin_amdgcn_rcpf(cos_i + 1e-12f);
    const float inv_Rd   = __builtin_amdgcn_rcpf(Rd);
    const float inv_Rt   = __builtin_amdgcn_rcpf(Rt);
    const float vfac     = vmax * (float)(2.0 / M_PI) * sin_i;

    // grid constants
    const float PIX   = (float)(0.05 / 4.0);
    const float FOVH  = (float)(0.5 * (NPH - 1) * (0.05 / 4.0));     // 3.19375
    const float VEL0  = (float)(-320.0 - 0.5 * (10.0 - 10.0 / 4.0)); // -323.75
    const float INVDV = 0.4f;

    // per-thread uniform quantile offsets in BIN units
    const float sdv = sig * INVDV;
    float cks[KQ];
    #pragma unroll
    for (int k = 0; k < KQ; ++k) cks[k] = sdv * units.u[k];

    // ---- per-thread hi-res pixel ----
    const int tx  = tid & 63;          // hi x within tile
    const int ty  = tid >> 6;          // hi y within lo row
    const int lp  = tx >> 2;           // lo pixel within tile
    const int xhi = blockIdx.x * 64 + tx;
    const int yhi = blockIdx.y * 4  + ty;

    const float thx = -FOVH + PIX * (float)xhi;
    const float thy = -FOVH + PIX * (float)yhi;

    // SIS raytrace: beta = theta * (1 - thE/r)
    const float r    = sqrtf(thx * thx + thy * thy) + 1e-12f;
    const float defl = thE * __builtin_amdgcn_rcpf(r);
    const float bx   = thx - thx * defl;
    const float by   = thy - thy * defl;

    // invert sky projection
    const float X  = (bx - x0) * inv_aspp;
    const float Y  = (by - y0) * inv_aspp;
    const float xg =  cp * X + sp * Y;
    const float yg = (-sp * X + cp * Y) * inv_cosi;
    const float R  = sqrtf(xg * xg + yg * yg);

    // analytic intensity / LOS velocity
    const float Iw    = I0 * __expf(-R * inv_Rd);
    const float vc    = vfac * fast_atan_pos(R * inv_Rt);
    const float xfrac = xg * __builtin_amdgcn_rcpf(R + 1e-12f);
    const float vlos  = vc * xfrac + vsh;

    const float base_ivf = (vlos - VEL0) * INVDV;

    __syncthreads();   // histograms zeroed

    // ---- K quantile channels -> linear binning, folded to lo bins ----
    float* h = hist[lp];
    #pragma unroll
    for (int k = 0; k < KQ; ++k) {
        const float ivf  = base_ivf + cks[k];
        const float iv0f = fminf(floorf(fmaxf(ivf, 0.0f)), 255.0f);
        const int   iv0  = (int)iv0f;
        const int   iv1  = iv0 + 1 > NVH - 1 ? NVH - 1 : iv0 + 1;
        const int   l0   = iv0 >> 2;
        const int   l1   = iv1 >> 2;
        if (l0 == l1) {
            // both interp endpoints in the same lo bin: weights sum to Iw
            lds_fadd(&h[l0], Iw);
        } else {
            // split path implies 0 <= ivf < 255 with iv0 = floor(ivf),
            // so fv in [0,1) needs no clamping
            const float fv = ivf - iv0f;
            const float w1 = Iw * fv;
            lds_fadd(&h[l0], Iw - w1);
            lds_fadd(&h[l1], w1);
        }
    }

    __syncthreads();

    // ---- store: 1024 outputs/block, scale by 1/(K * 4*4*4) = 1/512 ----
    const int xbase = blockIdx.x * 16;
    const int ybase = (int)blockIdx.y * NPL;
    #pragma unroll
    for (int p = 0; p < 4; ++p) {
        const int o   = tid + 256 * p;
        const int v   = o >> 4;
        const int flp = o & 15;
        out[v * (NPL * NPL) + ybase + xbase + flp] = hist[flp][v] * (1.0f / 512.0f);
    }
}

// host-side double-precision erfinv via Winitzki guess + Newton on std::erf
double erfinv_newton(double y) {
    if (y == 0.0) return 0.0;
    const double a  = 0.147;
    const double ln = std::log(1.0 - y * y);
    const double t  = 2.0 / (M_PI * a) + 0.5 * ln;
    double x = std::sqrt(std::sqrt(t * t - ln / a) - t);
    if (y < 0.0) x = -x;
    for (int i = 0; i < 4; ++i) {
        const double err = std::erf(x) - y;
        x -= err / (2.0 / std::sqrt(M_PI) * std::exp(-x * x));
    }
    return x;
}

} // namespace

extern "C" void kernel_launch(void* const* d_in, const int* in_sizes, int n_in,
                              void* d_out, int out_size, void* d_ws, size_t ws_size,
                              hipStream_t stream) {
    Units u;
    for (int k = 0; k < KQ; ++k) {
        const double p = (k + 0.5) / (double)KQ;
        u.u[k] = (float)(std::sqrt(2.0) * erfinv_newton(2.0 * p - 1.0));
    }

    const float* p_inc  = (const float*)d_in[0];
    const float* p_rot  = (const float*)d_in[1];
    const float* p_sig  = (const float*)d_in[2];
    const float* p_vsh  = (const float*)d_in[3];
    const float* p_x0   = (const float*)d_in[4];
    const float* p_y0   = (const float*)d_in[5];
    const float* p_dist = (const float*)d_in[6];
    const float* p_thE  = (const float*)d_in[7];
    const float* p_I0   = (const float*)d_in[8];
    const float* p_Rd   = (const float*)d_in[9];
    const float* p_vmax = (const float*)d_in[10];
    const float* p_Rt   = (const float*)d_in[11];

    dim3 grid(NPH / 64, NPH / 4);   // (8, 128) = 1024 blocks
    dim3 block(256);
    lens_cube_kernel<<<grid, block, 0, stream>>>(
        p_inc, p_rot, p_sig, p_vsh, p_x0, p_y0, p_dist, p_thE,
        p_I0, p_Rd, p_vmax, p_Rt, (float*)d_out, u);
}

// Round 4
// 24.733 us; speedup vs baseline: 1.3759x; 1.0255x over previous
//
#include <hip/hip_runtime.h>
#include <cmath>

namespace {

constexpr int KQ   = 8;     // quantile subchannels
constexpr int NVH  = 256;   // hi-res velocity bins
constexpr int NVL  = 64;    // lo-res velocity bins
constexpr int NPH  = 512;   // hi-res image size
constexpr int NPL  = 128;   // lo-res image size
constexpr int TLX  = 32;    // lo pixels per block (x)
constexpr int HPAD = NVL + 1; // 65: stride-65 spreads banks fully

struct Units { float u[KQ]; };

__device__ __forceinline__ void lds_fadd(float* p, float v) {
    // Relaxed workgroup-scope fp add on LDS -> native ds_add_f32 (no CAS loop).
    __hip_atomic_fetch_add(p, v, __ATOMIC_RELAXED, __HIP_MEMORY_SCOPE_WORKGROUP);
}

// fast atan for x >= 0: odd minimax poly on [0,1], rcp range-reduction above 1.
__device__ __forceinline__ float fast_atan_pos(float x) {
    const bool big = x > 1.0f;
    const float z  = big ? __builtin_amdgcn_rcpf(x) : x;   // z in [0,1]
    const float s  = z * z;
    float p = -0.0117212f;
    p = fmaf(p, s,  0.05265332f);
    p = fmaf(p, s, -0.11643287f);
    p = fmaf(p, s,  0.19354346f);
    p = fmaf(p, s, -0.33262347f);
    p = fmaf(p, s,  0.99997726f);
    const float a = p * z;
    return big ? (float)(M_PI / 2.0) - a : a;
}

__global__ __launch_bounds__(256)
void lens_cube_kernel(const float* __restrict__ p_inc,
                      const float* __restrict__ p_rot,
                      const float* __restrict__ p_sig,
                      const float* __restrict__ p_vsh,
                      const float* __restrict__ p_x0,
                      const float* __restrict__ p_y0,
                      const float* __restrict__ p_dist,
                      const float* __restrict__ p_thE,
                      const float* __restrict__ p_I0,
                      const float* __restrict__ p_Rd,
                      const float* __restrict__ p_vmax,
                      const float* __restrict__ p_Rt,
                      float* __restrict__ out,
                      Units units)
{
    // 32 lo pixels per block, 64-bin lo-res histogram each.
    // Lane map: wave = one hi-y row, lanes 2i,2i+1 -> lo pixel i
    // -> atomics per wave hit 32 DIFFERENT stride-65 histograms (banks spread,
    //    <=2-way aliasing = free).
    __shared__ float hist[TLX][HPAD];   // 8.3 KB

    const int tid = threadIdx.x;

    // ---- zero histograms (2080 words) ----
    float* hflat = &hist[0][0];
    for (int i = tid; i < TLX * HPAD; i += 256) hflat[i] = 0.0f;

    // ---- scalar params (uniform broadcast loads) ----
    const float inc  = *p_inc;
    const float rot  = *p_rot;
    const float sig  = fabsf(*p_sig) + 1e-12f;
    const float vsh  = *p_vsh;
    const float x0   = *p_x0;
    const float y0   = *p_y0;
    const float dist = *p_dist;
    const float thE  = *p_thE;
    const float I0   = *p_I0;
    const float Rd   = *p_Rd;
    const float vmax = *p_vmax;
    const float Rt   = *p_Rt;

    const float sin_i = __sinf(inc);
    const float cos_i = __cosf(inc);
    const float pa    = rot + (float)(M_PI / 2.0);
    const float sp    = __sinf(pa);
    const float cp    = __cosf(pa);

    const float inv_aspp = dist * (float)(1.0 / 206265.0);  // pc per arcsec
    const float inv_cosi = __builtin_amdgcn_rcpf(cos_i + 1e-12f);
    const float inv_Rd   = __builtin_amdgcn_rcpf(Rd);
    const float inv_Rt   = __builtin_amdgcn_rcpf(Rt);
    const float vfac     = vmax * (float)(2.0 / M_PI) * sin_i;

    // grid constants
    const float PIX   = (float)(0.05 / 4.0);
    const float FOVH  = (float)(0.5 * (NPH - 1) * (0.05 / 4.0));     // 3.19375
    const float VEL0  = (float)(-320.0 - 0.5 * (10.0 - 10.0 / 4.0)); // -323.75
    const float INVDV = 0.4f;

    // quantile offsets in bin units
    const float sdv = sig * INVDV;
    float cks[KQ];
    #pragma unroll
    for (int k = 0; k < KQ; ++k) cks[k] = sdv * units.u[k];

    // ---- thread -> (hi_y, lo pixel, half) ; 2 hi-x pixels per thread ----
    const int hy  = tid >> 6;          // 0..3  hi y within lo row
    const int s   = tid & 63;
    const int lp  = s >> 1;            // 0..31 lo pixel within tile
    const int hf  = s & 1;             // which hi-x pair
    const int xh0 = blockIdx.x * (TLX * 4) + lp * 4 + hf * 2;
    const int yhi = blockIdx.y * 4 + hy;

    const float thy = fmaf(PIX, (float)yhi, -FOVH);
    float* h = hist[lp];

    __syncthreads();   // histograms zeroed

    #pragma unroll
    for (int j = 0; j < 2; ++j) {
        const float thx = fmaf(PIX, (float)(xh0 + j), -FOVH);

        // SIS raytrace: beta = theta * (1 - thE/r)
        const float r    = sqrtf(thx * thx + thy * thy) + 1e-12f;
        const float defl = thE * __builtin_amdgcn_rcpf(r);
        const float bx   = thx - thx * defl;
        const float by   = thy - thy * defl;

        // invert sky projection
        const float X  = (bx - x0) * inv_aspp;
        const float Y  = (by - y0) * inv_aspp;
        const float xg =  cp * X + sp * Y;
        const float yg = (-sp * X + cp * Y) * inv_cosi;
        const float R  = sqrtf(xg * xg + yg * yg);

        // analytic intensity / LOS velocity
        const float Iw    = I0 * __expf(-R * inv_Rd);
        const float vc    = vfac * fast_atan_pos(R * inv_Rt);
        const float xfrac = xg * __builtin_amdgcn_rcpf(R + 1e-12f);
        const float vlos  = vc * xfrac + vsh;

        const float base_ivf = (vlos - VEL0) * INVDV;

        // ---- K quantile channels -> linear binning, folded to lo bins ----
        #pragma unroll
        for (int k = 0; k < KQ; ++k) {
            const float ivf  = base_ivf + cks[k];
            const float iv0f = fminf(floorf(fmaxf(ivf, 0.0f)), 255.0f);
            const int   iv0  = (int)iv0f;
            const int   iv1  = iv0 + 1 > NVH - 1 ? NVH - 1 : iv0 + 1;
            const int   l0   = iv0 >> 2;
            const int   l1   = iv1 >> 2;
            if (l0 == l1) {
                // both interp endpoints in the same lo bin: weights sum to Iw
                lds_fadd(&h[l0], Iw);
            } else {
                // split path implies 0 <= ivf < 255, so fv in [0,1)
                const float fv = ivf - iv0f;
                const float w1 = Iw * fv;
                lds_fadd(&h[l0], Iw - w1);
                lds_fadd(&h[l1], w1);
            }
        }
    }

    __syncthreads();

    // ---- store: 64 v x 32 x = 2048 floats; two 128B runs per wave-store ----
    const int xbase = blockIdx.x * TLX;
    const int ybase = (int)blockIdx.y * NPL;
    #pragma unroll
    for (int p = 0; p < 8; ++p) {
        const int o = p * 256 + tid;
        const int v = o >> 5;          // 0..63
        const int x = o & 31;
        // hist[x][v]: lane->addr = x*65+v -> all 32 banks, 2-way (free)
        out[v * (NPL * NPL) + ybase + xbase + x] = hist[x][v] * (1.0f / 512.0f);
    }
}

// host-side double-precision erfinv via Winitzki guess + Newton on std::erf
double erfinv_newton(double y) {
    if (y == 0.0) return 0.0;
    const double a  = 0.147;
    const double ln = std::log(1.0 - y * y);
    const double t  = 2.0 / (M_PI * a) + 0.5 * ln;
    double x = std::sqrt(std::sqrt(t * t - ln / a) - t);
    if (y < 0.0) x = -x;
    for (int i = 0; i < 4; ++i) {
        const double err = std::erf(x) - y;
        x -= err / (2.0 / std::sqrt(M_PI) * std::exp(-x * x));
    }
    return x;
}

} // namespace

extern "C" void kernel_launch(void* const* d_in, const int* in_sizes, int n_in,
                              void* d_out, int out_size, void* d_ws, size_t ws_size,
                              hipStream_t stream) {
    Units u;
    for (int k = 0; k < KQ; ++k) {
        const double p = (k + 0.5) / (double)KQ;
        u.u[k] = (float)(std::sqrt(2.0) * erfinv_newton(2.0 * p - 1.0));
    }

    const float* p_inc  = (const float*)d_in[0];
    const float* p_rot  = (const float*)d_in[1];
    const float* p_sig  = (const float*)d_in[2];
    const float* p_vsh  = (const float*)d_in[3];
    const float* p_x0   = (const float*)d_in[4];
    const float* p_y0   = (const float*)d_in[5];
    const float* p_dist = (const float*)d_in[6];
    const float* p_thE  = (const float*)d_in[7];
    const float* p_I0   = (const float*)d_in[8];
    const float* p_Rd   = (const float*)d_in[9];
    const float* p_vmax = (const float*)d_in[10];
    const float* p_Rt   = (const float*)d_in[11];

    dim3 grid(NPH / (TLX * 4), NPH / 4);   // (4, 128) = 512 blocks
    dim3 block(256);
    lens_cube_kernel<<<grid, block, 0, stream>>>(
        p_inc, p_rot, p_sig, p_vsh, p_x0, p_y0, p_dist, p_thE,
        p_I0, p_Rd, p_vmax, p_Rt, (float*)d_out, u);
}